// Round 12
// baseline (144.477 us; speedup 1.0000x reference)
//
#include <hip/hip_runtime.h>
#include <math.h>

// Problem constants (static per reference)
#define NPG     512
#define B_GR    512
#define FDIM    255
#define DEG     32
#define EPG     (NPG * DEG)       // 16384 edges per graph (graph-contiguous)
#define N_NODES (B_GR * NPG)      // 262144
#define E_TOT   (N_NODES * DEG)   // 8388608
#define K_KEEP  256               // ceil(0.5 * NPG)

// ---------------------------------------------------------------------------
// 2-graph software pipeline: 256 blocks x 1024 threads, block b owns graphs
// g1=2b, g2=2b+1.
//   head   : A(g1) — barrier-free streaming matvec, all 16 waves
//   overlap: 8 regions; waves 0-7 run BCD(g1) stages (512-wide) while
//            waves 8-15 stream A(g2) slices (barrier-free). One block-wide
//            __syncthreads per region keeps both halves aligned.
//   tail   : D(g1), then BCD(g2) + D(g2) full-width (proven 1024-wide code).
// The latency-bound BCD(g1) hides under g2's BW streaming.
// ---------------------------------------------------------------------------
__global__ __launch_bounds__(1024, 4) void k_fused(const float* __restrict__ feat,
                                                   const int*   __restrict__ z,
                                                   const int*   __restrict__ ei,
                                                   const float* __restrict__ W,
                                                   const float* __restrict__ bias,
                                                   float*       __restrict__ outp) {
    __shared__ ushort4 cc4[EPG / 4];              // 32 KB col cache (per graph, reused)
    __shared__ __align__(16) float Wx[1020];      // Wx[i] = W[i % 255]
    __shared__ __align__(16) float score[NPG];
    __shared__ __align__(16) float v1[NPG];       // g1: h, later v=dinv*h
    __shared__ __align__(16) float v2[NPG];       // g2: h, later v=dinv*h
    __shared__ float dinv_l[NPG];
    __shared__ float agg[NPG];
    __shared__ float realb1[NPG];
    __shared__ float realb2[NPG];
    __shared__ int   deg[NPG];                    // g1 deg -> g1 rank -> g2 deg
    __shared__ int   rank2[2][NPG];               // g2 full-width rank split
    __shared__ int   selidx[K_KEEP];
    __shared__ float selsc[K_KEEP];
    __shared__ float red[3][256];
    __shared__ float w255s;
    __shared__ int   cnt;

    const int b    = blockIdx.x;
    const int g1   = 2 * b, g2 = 2 * b + 1;
    const int tid  = threadIdx.x;
    const int lane = tid & 63;
    const int wave = tid >> 6;
    const int nb1  = g1 * NPG, nb2 = g2 * NPG;

    // ---------------- preamble ----------------
    if (tid < 1020) Wx[tid] = W[tid % 255];
    if (tid == 0) w255s = W[255];
    if (tid < NPG) {
        realb1[tid] = (z[nb1 + tid] != 100) ? 1.f : 0.f;
        deg[tid]    = 1;                      // g1 self-loop
    } else {
        realb2[tid - NPG] = (z[nb2 + tid - NPG] != 100) ? 1.f : 0.f;
    }
    __syncthreads();

    const bool   l63   = (lane == 63);
    const float4 zero4 = make_float4(0.f, 0.f, 0.f, 0.f);
    const float4* W4   = (const float4*)Wx;
    const float4 wf0 = W4[lane];
    const float4 wf1 = W4[64 + lane];
    const float4 wf2 = W4[128 + lane];
    const float4 wf3 = l63 ? zero4 : W4[192 + lane];
    const float  w255 = w255s;
    const float  bb0  = bias[0];

    // barrier-free 4-row-group projection (R11-verified arithmetic)
    auto proj_group = [&](const float4* F4, const float* rb, float4* vout, int grp) {
        const float4* src = F4 + (size_t)grp * 255;
        const float4 a = src[lane];
        const float4 bq = src[64 + lane];
        const float4 c = src[128 + lane];
        const float4 d = l63 ? zero4 : src[192 + lane];

        float acc0 = a.x * wf0.x + a.y * wf0.y + a.z * wf0.z;
        const float p03 = a.w * wf0.w;
        float acc1 = bq.x * wf1.x + bq.y * wf1.y;
        const float p12 = bq.z * wf1.z, p13 = bq.w * wf1.w;
        float acc2 = c.x * wf2.x;
        const float p21 = c.y * wf2.y, p22 = c.z * wf2.z, p23 = c.w * wf2.w;
        float acc3 = d.x * wf3.x + d.y * wf3.y + d.z * wf3.z + d.w * wf3.w;

        const float q1 = p12 + p13;
        const float q2 = p21 + p22 + p23;
        acc0 += l63 ? 0.f : p03;
        acc1 += l63 ? p03 : q1;
        acc2 += l63 ? q1  : q2;
        acc3 += l63 ? q2  : 0.f;

#pragma unroll
        for (int off = 32; off; off >>= 1) {
            acc0 += __shfl_down(acc0, off, 64);
            acc1 += __shfl_down(acc1, off, 64);
            acc2 += __shfl_down(acc2, off, 64);
            acc3 += __shfl_down(acc3, off, 64);
        }
        if (lane == 0) {
            const int n0 = grp * 4;
            float4 hv;
            hv.x = acc0 + rb[n0 + 0] * w255;
            hv.y = acc1 + rb[n0 + 1] * w255;
            hv.z = acc2 + rb[n0 + 2] * w255;
            hv.w = acc3 + rb[n0 + 3] * w255;
            vout[grp] = hv;
        }
    };

    // ---------------- head: A(g1), all 16 waves ----------------
    {
        const float4* F4 = (const float4*)(feat + (size_t)nb1 * FDIM);
        float4* vo = (float4*)v1;
        for (int k = 0; k < 8; ++k)
            proj_group(F4, realb1, vo, wave + (k << 4));
    }
    __syncthreads();

    const int4* colp1 = (const int4*)(ei + (size_t)E_TOT + (size_t)g1 * EPG);
    const int4* rowp1 = (const int4*)(ei + (size_t)g1 * EPG);

    // ---------------- overlap: BCD(g1) 512-wide || A(g2) ----------------
    for (int r = 0; r < 8; ++r) {
        if (wave < 8) {
            switch (r) {
            case 0: case 1: {                 // pass1: col cache + deg
                for (int it = r * 4; it < r * 4 + 4; ++it) {
                    const int  idx = it * 512 + tid;
                    const int4 c4  = colp1[idx];
                    ushort4 u;
                    u.x = (unsigned short)(c4.x - nb1);
                    u.y = (unsigned short)(c4.y - nb1);
                    u.z = (unsigned short)(c4.z - nb1);
                    u.w = (unsigned short)(c4.w - nb1);
                    cc4[idx] = u;
                    atomicAdd(&deg[u.x], 1);
                    atomicAdd(&deg[u.y], 1);
                    atomicAdd(&deg[u.z], 1);
                    atomicAdd(&deg[u.w], 1);
                }
            } break;
            case 2: {                         // dinv + v + agg init
                const float di = (float)(1.0 / sqrt((double)deg[tid]));
                dinv_l[tid] = di;
                const float v = di * v1[tid];
                v1[tid] = v;
                agg[tid] = v;
                if (tid == 0) cnt = 0;
            } break;
            case 3: case 4: {                 // pass2: agg[c] += v[r]
                for (int it = (r - 3) * 4; it < (r - 3) * 4 + 4; ++it) {
                    const int     idx = it * 512 + tid;
                    const int4    r4  = rowp1[idx];
                    const ushort4 u   = cc4[idx];
                    atomicAdd(&agg[u.x], v1[r4.x - nb1]);
                    atomicAdd(&agg[u.y], v1[r4.y - nb1]);
                    atomicAdd(&agg[u.z], v1[r4.z - nb1]);
                    atomicAdd(&agg[u.w], v1[r4.w - nb1]);
                }
            } break;
            case 5:                           // score
                score[tid] = tanhf(fmaf(agg[tid], dinv_l[tid], bb0));
                break;
            case 6: {                         // rank (each thread: 512 compares)
                const float   sc  = score[tid];
                const float4* s4p = (const float4*)score;
                int part = 0;
                for (int i = 0; i < 128; ++i) {
                    const float4 s4 = s4p[i];          // broadcast b128
                    const int    j  = i * 4;
                    part += (s4.x > sc) || (s4.x == sc && (j + 0) < tid);
                    part += (s4.y > sc) || (s4.y == sc && (j + 1) < tid);
                    part += (s4.z > sc) || (s4.z == sc && (j + 2) < tid);
                    part += (s4.w > sc) || (s4.w == sc && (j + 3) < tid);
                }
                deg[tid] = part;              // deg reused as rank store
            } break;
            case 7: {                         // select (jax tie-break)
                if (deg[tid] < K_KEEP) {
                    const int slot = atomicAdd(&cnt, 1);
                    selidx[slot] = tid;
                    selsc[slot]  = score[tid];
                }
            } break;
            }
        } else {
            // A(g2) slice r: wave'=wave-8 handles groups w'*16 + 2r, 2r+1
            const float4* F4 = (const float4*)(feat + (size_t)nb2 * FDIM);
            float4* vo = (float4*)v2;
            const int w16 = (wave - 8) * 16;
            proj_group(F4, realb2, vo, w16 + 2 * r);
            proj_group(F4, realb2, vo, w16 + 2 * r + 1);
        }
        __syncthreads();
    }

    // ---------------- D(g1): full-width 8-batched gather ----------------
    {
        const int f = tid & 255;
        const int q = tid >> 8;
        float acc = 0.f;
        if (f < FDIM) {
            const float* fb = feat + (size_t)nb1 * FDIM + f;
#pragma unroll
            for (int k = 0; k < 64; k += 8) {
                int   is[8]; float ss[8]; float tv[8];
#pragma unroll
                for (int j = 0; j < 8; ++j) {
                    is[j] = selidx[q + 4 * (k + j)];
                    ss[j] = selsc [q + 4 * (k + j)];
                }
#pragma unroll
                for (int j = 0; j < 8; ++j)
                    tv[j] = fb[(size_t)is[j] * FDIM];
#pragma unroll
                for (int j = 0; j < 8; ++j)
                    acc = fmaf(ss[j], tv[j], acc);
            }
        } else {
            for (int s = q; s < K_KEEP; s += 4)
                acc = fmaf(selsc[s], realb1[selidx[s]], acc);
        }
        if (q) red[q - 1][f] = acc;
        if (tid < NPG) deg[tid] = 1;          // re-init for g2 (g1 rank dead)
        if (tid == 0)  cnt = 0;               // re-init for g2
        __syncthreads();
        if (q == 0)
            outp[(size_t)g1 * 256 + f] =
                (acc + red[0][f] + red[1][f] + red[2][f]) * (1.f / K_KEEP);
    }
    __syncthreads();   // red/selidx/selsc reads done before g2 reuse

    // ---------------- BCD(g2) + D(g2): full-width (R9-proven) ----------
    const int4* colp2 = (const int4*)(ei + (size_t)E_TOT + (size_t)g2 * EPG);
    const int4* rowp2 = (const int4*)(ei + (size_t)g2 * EPG);

    {
        int4 c4v[4], r4v[4];
#pragma unroll
        for (int it = 0; it < 4; ++it) c4v[it] = colp2[it * 1024 + tid];
#pragma unroll
        for (int it = 0; it < 4; ++it) r4v[it] = rowp2[it * 1024 + tid];

#pragma unroll
        for (int it = 0; it < 4; ++it) {
            const int4 c4 = c4v[it];
            ushort4 u;
            u.x = (unsigned short)(c4.x - nb2);
            u.y = (unsigned short)(c4.y - nb2);
            u.z = (unsigned short)(c4.z - nb2);
            u.w = (unsigned short)(c4.w - nb2);
            cc4[it * 1024 + tid] = u;
            atomicAdd(&deg[u.x], 1);
            atomicAdd(&deg[u.y], 1);
            atomicAdd(&deg[u.z], 1);
            atomicAdd(&deg[u.w], 1);
        }
        __syncthreads();

        if (tid < NPG) {
            const float di = (float)(1.0 / sqrt((double)deg[tid]));
            dinv_l[tid] = di;
            const float v = di * v2[tid];
            v2[tid] = v;
            agg[tid] = v;
        }
        __syncthreads();

#pragma unroll
        for (int it = 0; it < 4; ++it) {
            const ushort4 u  = cc4[it * 1024 + tid];
            const int4    r4 = r4v[it];
            atomicAdd(&agg[u.x], v2[r4.x - nb2]);
            atomicAdd(&agg[u.y], v2[r4.y - nb2]);
            atomicAdd(&agg[u.z], v2[r4.z - nb2]);
            atomicAdd(&agg[u.w], v2[r4.w - nb2]);
        }
        __syncthreads();
    }

    if (tid < NPG)
        score[tid] = tanhf(fmaf(agg[tid], dinv_l[tid], bb0));
    __syncthreads();

    {
        const int     node = tid & (NPG - 1);
        const int     half = tid >> 9;
        const float   sc   = score[node];
        const float4* s4p  = (const float4*)&score[half * 256];
        int part = 0;
#pragma unroll 8
        for (int i = 0; i < 64; ++i) {
            const float4 s4 = s4p[i];
            const int    j  = half * 256 + i * 4;
            part += (s4.x > sc) || (s4.x == sc && (j + 0) < node);
            part += (s4.y > sc) || (s4.y == sc && (j + 1) < node);
            part += (s4.z > sc) || (s4.z == sc && (j + 2) < node);
            part += (s4.w > sc) || (s4.w == sc && (j + 3) < node);
        }
        rank2[half][node] = part;
    }
    __syncthreads();

    if (tid < NPG) {
        const int rank = rank2[0][tid] + rank2[1][tid];
        if (rank < K_KEEP) {
            const int slot = atomicAdd(&cnt, 1);
            selidx[slot] = tid;
            selsc[slot]  = score[tid];
        }
    }
    __syncthreads();

    {
        const int f = tid & 255;
        const int q = tid >> 8;
        float acc = 0.f;
        if (f < FDIM) {
            const float* fb = feat + (size_t)nb2 * FDIM + f;
#pragma unroll
            for (int k = 0; k < 64; k += 8) {
                int   is[8]; float ss[8]; float tv[8];
#pragma unroll
                for (int j = 0; j < 8; ++j) {
                    is[j] = selidx[q + 4 * (k + j)];
                    ss[j] = selsc [q + 4 * (k + j)];
                }
#pragma unroll
                for (int j = 0; j < 8; ++j)
                    tv[j] = fb[(size_t)is[j] * FDIM];
#pragma unroll
                for (int j = 0; j < 8; ++j)
                    acc = fmaf(ss[j], tv[j], acc);
            }
        } else {
            for (int s = q; s < K_KEEP; s += 4)
                acc = fmaf(selsc[s], realb2[selidx[s]], acc);
        }
        if (q) red[q - 1][f] = acc;
        __syncthreads();
        if (q == 0)
            outp[(size_t)g2 * 256 + f] =
                (acc + red[0][f] + red[1][f] + red[2][f]) * (1.f / K_KEEP);
    }
}

extern "C" void kernel_launch(void* const* d_in, const int* in_sizes, int n_in,
                              void* d_out, int out_size, void* d_ws, size_t ws_size,
                              hipStream_t stream) {
    const float* feat = (const float*)d_in[0];   // out: [N, F] f32
    const int*   z    = (const int*)  d_in[1];   // z:   [N] i32
    const int*   ei   = (const int*)  d_in[2];   // edge_index: [2, E] i32
    // d_in[3] = batch (unused), d_in[6] = edge_attr (unused)
    const float* W    = (const float*)d_in[4];   // [F+1] f32
    const float* bias = (const float*)d_in[5];   // [1] f32
    float* outp = (float*)d_out;                 // [B, F+1] f32

    k_fused<<<B_GR / 2, 1024, 0, stream>>>(feat, z, ei, W, bias, outp);
}